// Round 11
// baseline (26.621 us; speedup 1.0000x reference)
//
#include <hip/hip_runtime.h>
#include <math.h>

#define NB 4
#define FRAMES 400
#define NBINS 129
#define HOP 240
#define T_LEN (FRAMES * HOP)   // 96000
#define KLEN 256               // FIR length = 2*(NBINS-1)

#define REC_C { const float cn_ = fmaf(a2, cm, -cm1); cm1 = cm; cm = cn_; }
#define REC_S { const float sn_ = fmaf(a2, sm, -sm1); sm1 = sm; sm = sn_; }

typedef float v2f __attribute__((ext_vector_type(2)));

// packed fp32 FMA, x-operand splatted via op_sel (no v_mov):
//   PK_YY: acc += (x.y, x.y) * k2    PK_XX: acc += (x.x, x.x) * k2
#define PK_YY(acc, xv, kk) \
    asm("v_pk_fma_f32 %0, %1, %2, %0 op_sel:[1,0,0] op_sel_hi:[1,1,1]" \
        : "+v"(acc) : "v"(xv), "v"(kk))
#define PK_XX(acc, xv, kk) \
    asm("v_pk_fma_f32 %0, %1, %2, %0 op_sel:[0,0,0] op_sel_hi:[0,1,1]" \
        : "+v"(acc) : "v"(xv), "v"(kk))

// ---------------------------------------------------------------------------
// Kernel 1: R10 gen with loop 1 moved OFF the LDS pipe: lm[] is read via the
// block-uniform pointer (s_load chain, SMEM). Loops 2/3 keep float4 LDS
// broadcasts of block-computed data. Parity split (thread n -> ker[n],
// ker[n+128]); Chebyshev recurrences; HW trig in revolutions. Identical FMA
// order to R10 -> bit-identical kernels.
// ---------------------------------------------------------------------------
__global__ __launch_bounds__(128) void gen_fir(const float* __restrict__ log_mag,
                                               float* __restrict__ kern) {
    const int bf = blockIdx.x;   // 0..NB*FRAMES-1
    const int n  = threadIdx.x;  // 0..127

    __shared__ __align__(16) float  g[128];      // Xf[k]/128
    __shared__ __align__(16) float2 crci[128];   // (wC[k], wS[k]); w=1 at k=0 else 2

    const float* lm = log_mag + bf * NBINS;      // block-uniform -> s_load

    const float lmn = lm[n];                     // per-lane coalesced
    const float rev_n = (float)n * (1.0f / 256.0f);
    const float ca = __builtin_amdgcn_cosf(rev_n);   // cos(2*pi*n/256)
    const float sa = __builtin_amdgcn_sinf(rev_n);
    const float a2  = 2.0f * ca;
    const float sgn = (n & 1) ? -1.0f : 1.0f;        // (-1)^n

    const float full0   = lm[0];                 // uniform scalars
    const float full128 = lm[128];

    // ---- Xf[n] = 2*sum_{m=0..127} lm[m] cos(mna) - lm[0] + sgn*lm[128]
    {
        float cm1 = ca, cm = 1.0f, acc = 0.0f;       // c_{-1}=cos(-a), c_0=1
#pragma unroll 8
        for (int m = 0; m < 128; ++m) {
            acc = fmaf(lm[m], cm, acc);              // uniform -> SGPR operand
            REC_C;
        }
        const float Xf = 2.0f * acc - full0 + sgn * full128;
        g[n] = Xf * (1.0f / 128.0f);
    }
    __syncthreads();

    // ---- mp[n] = -sum_{k=0..127} g[k] sin(kna)   (k=0 term is 0)
    {
        const float4* g4p = (const float4*)g;
        float sm1 = -sa, sm = 0.0f, acc = 0.0f;      // s_{-1}=sin(-a), s_0=0
#pragma unroll 8
        for (int u = 0; u < 32; ++u) {
            const float4 gv = g4p[u];
            acc = fmaf(gv.x, sm, acc); REC_S;
            acc = fmaf(gv.y, sm, acc); REC_S;
            acc = fmaf(gv.z, sm, acc); REC_S;
            acc = fmaf(gv.w, sm, acc); REC_S;
        }
        const float mp = -acc;
        const float e  = __builtin_amdgcn_exp2f(lmn * 1.4426950408889634f);
        float rev = mp * 0.15915494309189535f;       // mp / (2*pi)
        rev = rev - floorf(rev);                     // v_fract reduction
        const float smp  = __builtin_amdgcn_sinf(rev);
        const float cmp_ = __builtin_amdgcn_cosf(rev);
        const float sc = (n == 0) ? 1.0f : 2.0f;
        crci[n] = make_float2(sc * e * cmp_, sc * e * smp);
    }
    __syncthreads();

    // ---- ker[n]     = (accE + accO + sgn*e128)/256          (hann = 1)
    //      ker[n+128] = (accE - accO + sgn*e128)/256*(0.5+0.5ca)
    {
        const float e128 = __builtin_amdgcn_exp2f(full128 * 1.4426950408889634f);
        const float4* cc4 = (const float4*)crci;
        float cm1 = ca, cm = 1.0f;     // k=0
        float sm1 = -sa, sm = 0.0f;
        float accE = 0.0f, accO = 0.0f;
#pragma unroll 8
        for (int u = 0; u < 64; ++u) {
            const float4 q = cc4[u];   // C'[2u], S'[2u], C'[2u+1], S'[2u+1]
            accE = fmaf(q.x, cm, accE); accE = fmaf(-q.y, sm, accE);
            REC_C; REC_S;
            accO = fmaf(q.z, cm, accO); accO = fmaf(-q.w, sm, accO);
            REC_C; REC_S;
        }
        const float base = sgn * e128;
        const float s = 1.0f / 256.0f;
        kern[bf * KLEN + n]       = (accE + accO + base) * s;
        kern[bf * KLEN + n + 128] = (accE - accO + base) * s * (0.5f + 0.5f * ca);
    }
}

// ---------------------------------------------------------------------------
// Kernel 2: R3/R10 fir with v_pk_fma_f32 inner loop. kp stores (kL,kH)
// interleaved -> packed operand pairs; accumulators are (L,H) pairs; the x
// scalar is splatted via op_sel from the already-loaded float2 (zero movs).
// Per-chain FMA order identical to R10 -> bit-identical output.
// ---------------------------------------------------------------------------
__global__ __launch_bounds__(256) void fir_apply(const float* __restrict__ ex,
                                                 const float* __restrict__ kern,
                                                 float* __restrict__ out) {
    const int b   = blockIdx.y;
    const int t0  = blockIdx.x * 512;
    const int tid = threadIdx.x;

    __shared__ __align__(16) float  xs[768];        // x[t0-255 .. t0+256]
    __shared__ __align__(16) float2 kp[4][258];     // (kerLo[j], kerHi[j]) per q; +2 pad

    for (int i = tid; i < 768; i += 256) {
        const int t = t0 - 255 + i;
        xs[i] = (t >= 0 && t < T_LEN) ? ex[b * T_LEN + t] : 0.0f;
    }

    // frames needed by this block: f0 .. f0+3 (clamped)
    float src0 = ((float)t0 + 0.5f) * (1.0f / HOP) - 0.5f;
    src0 = fminf(fmaxf(src0, 0.0f), (float)(FRAMES - 1));
    const int f0 = (int)src0;
    const float* kb = kern + b * FRAMES * KLEN;
    for (int i = tid; i < 4 * KLEN; i += 256) {
        const int q = i >> 8;
        const int j = i & 255;
        const int fl = min(f0 + q,     FRAMES - 1);
        const int fh = min(f0 + q + 1, FRAMES - 1);
        kp[q][j] = make_float2(kb[fl * KLEN + j], kb[fh * KLEN + j]);
    }
    __syncthreads();

    const int te = t0 + 2 * tid;
    float se = ((float)te + 0.5f) * (1.0f / HOP) - 0.5f;
    se = fminf(fmaxf(se, 0.0f), (float)(FRAMES - 1));
    float so = ((float)te + 1.5f) * (1.0f / HOP) - 0.5f;
    so = fminf(fmaxf(so, 0.0f), (float)(FRAMES - 1));
    const int   lo = (int)se;           // == lo(te+1), boundary-safe by parity
    const float we = se - (float)lo;
    const float wo = so - (float)lo;

    const float4* kq4 = (const float4*)&kp[lo - f0][0];   // (kL[2u],kH[2u],kL[2u+1],kH[2u+1])

    const int base = 2 * tid;           // xs index of x[te] is base+255
    float2 pv = *(const float2*)&xs[base + 256];   // pv.x = x[te+1] (initial carry)
    v2f accE = {0.0f, 0.0f};            // (aeL, aeH)
    v2f accO = {0.0f, 0.0f};            // (aoL, aoH)
#pragma unroll 8
    for (int u = 0; u < 128; ++u) {
        const float2 v  = *(const float2*)&xs[base + 254 - 2 * u];  // (x[te-2u-1], x[te-2u])
        const float4 k4 = kq4[u];
        v2f k2a; k2a.x = k4.x; k2a.y = k4.y;   // (kL,kH) tap 2u
        v2f k2b; k2b.x = k4.z; k2b.y = k4.w;   // (kL,kH) tap 2u+1
        PK_YY(accE, v,  k2a);   // e, j=2u   : x = v.y
        PK_XX(accO, pv, k2a);   // o, j=2u   : x = carry (pv.x)
        PK_XX(accE, v,  k2b);   // e, j=2u+1 : x = v.x
        PK_YY(accO, v,  k2b);   // o, j=2u+1 : x = v.y
        pv = v;                 // carry = v.x for next u
    }
    const float aeL = accE.x, aeH = accE.y;
    const float aoL = accO.x, aoH = accO.y;

    if (te < T_LEN)     out[b * T_LEN + te]     = (1.0f - we) * aeL + we * aeH;
    if (te + 1 < T_LEN) out[b * T_LEN + te + 1] = (1.0f - wo) * aoL + wo * aoH;
}

// ---------------------------------------------------------------------------
extern "C" void kernel_launch(void* const* d_in, const int* in_sizes, int n_in,
                              void* d_out, int out_size, void* d_ws, size_t ws_size,
                              hipStream_t stream) {
    const float* ex      = (const float*)d_in[0];
    const float* log_mag = (const float*)d_in[1];
    float* kern = (float*)d_ws;          // NB*FRAMES*KLEN floats = 1.6 MB
    float* out  = (float*)d_out;

    gen_fir<<<NB * FRAMES, 128, 0, stream>>>(log_mag, kern);

    dim3 grid((T_LEN + 511) / 512, NB);
    fir_apply<<<grid, 256, 0, stream>>>(ex, kern, out);
}